// Round 12
// baseline (88.987 us; speedup 1.0000x reference)
//
#include <hip/hip_runtime.h>
#include <stdint.h>

#define CIN 256
#define COUT 128
#define BATCH 8
#define HH 64
#define WW 64
#define XROW 66

// xb2: padded bf16 input, [B][66 rows][66 cols][4 cb][8 slot][8 ch], slot pre-swizzled by (col&7)
#define XB2_BYTES ((size_t)BATCH * XROW * XROW * CIN * 2)
// gw3: fused weights, [9 taps][2 py][4 cb][256 row=co*2+px][8 slot][8 ch], slot pre-swizzled by (row&7)
#define GW3_BYTES ((size_t)9 * 2 * 4 * 256 * 64 * 2)

typedef __bf16 bf16x8 __attribute__((ext_vector_type(8)));
typedef float f32x4 __attribute__((ext_vector_type(4)));

__device__ __forceinline__ unsigned short f2bf(float f) {
  unsigned int u = __float_as_uint(f);
  u += 0x7fffu + ((u >> 16) & 1u);
  return (unsigned short)(u >> 16);
}

__device__ __forceinline__ void gload_lds16(const void* g, void* l) {
  __builtin_amdgcn_global_load_lds(
      (__attribute__((address_space(1))) void*)(uintptr_t)g,
      (__attribute__((address_space(3))) void*)l, 16, 0, 0);
}

// ---------------- fused prep: prep_x (512 blk) + prep_w (128 blk) + border (260 blk) ----------------
__global__ __launch_bounds__(256) void prep_all(const float* __restrict__ x,
                                                const float* __restrict__ w,
                                                const float* __restrict__ f,
                                                unsigned short* __restrict__ xb2,
                                                unsigned short* __restrict__ gw3) {
  __shared__ __align__(16) unsigned short lds[64][264];  // prep_x staging; fs aliases it
  const int blk = blockIdx.x;
  const int t = threadIdx.x;

  if (blk < 512) {
    // ---- prep_x: x -> padded channel-last swizzled bf16 (interior) ----
    int b = blk >> 6, iy = blk & 63;
    int cq = t >> 6, ix = t & 63;
    for (int ci = 0; ci < 64; ++ci) {
      int c = ci * 4 + cq;
      float v = x[(((size_t)b * CIN + c) * HH + iy) * WW + ix];
      lds[ix][c] = f2bf(v);
    }
    __syncthreads();
    for (int it = 0; it < 8; ++it) {
      int u = it * 256 + t;  // 2048 units of 16B: 64 ix * 32 (cb,slot)
      int ixo = u >> 5;
      int q = u & 31, cb = q >> 3, slot = q & 7;
      int col = ixo + 1;  // padded col
      int c0 = cb * 64 + 8 * (slot ^ (col & 7));
      uint4 val = *reinterpret_cast<const uint4*>(&lds[ixo][c0]);
      size_t o = ((((size_t)(b * XROW + (iy + 1)) * XROW + col) * 4 + cb) * 8 + slot) * 8;
      *reinterpret_cast<uint4*>(&xb2[o]) = val;
    }
  } else if (blk < 640) {
    // ---- prep_w: fuse He-scale * conv3x3 (x) FIR into per-parity 3x3 taps ----
    float* fs = (float*)lds;
    int co = blk - 512;
    int c = t;
    if (c < 16) fs[c] = f[c];
    __syncthreads();
    float wl[3][3];
    const float he = 1.0f / 48.0f;  // 1/sqrt(256*9)
#pragma unroll
    for (int dy = 0; dy < 3; ++dy)
#pragma unroll
      for (int dx = 0; dx < 3; ++dx)
        wl[dy][dx] = w[((size_t)(co * CIN + c) * 3 + dy) * 3 + dx] * he;
    int cb = c >> 6, cl = c & 63;
    int ce = cl & 7;
    for (int d = 0; d < 3; ++d)
      for (int e = 0; e < 3; ++e)
        for (int py = 0; py < 2; ++py)
          for (int px = 0; px < 2; ++px) {
            int ty = 2 * d + 1 - py, tx = 2 * e + 1 - px;  // taps of 6x6 composite g
            float acc = 0.f;
            for (int dy = 0; dy < 3; ++dy) {
              int a = ty - dy;
              if (a < 0 || a > 3) continue;
              for (int dx = 0; dx < 3; ++dx) {
                int bb = tx - dx;
                if (bb < 0 || bb > 3) continue;
                acc += wl[dy][dx] * fs[a * 4 + bb];
              }
            }
            int row = co * 2 + px;
            int slot = (cl >> 3) ^ (row & 7);
            size_t o =
                ((((size_t)(d * 3 + e) * 2 + py) * 4 + cb) * 256 + row) * 64 + slot * 8 + ce;
            gw3[o] = f2bf(acc);
          }
  } else {
    // ---- border zeroing ----
    int u = (blk - 640) * 256 + t;
    if (u >= 66560) return;
    int b = u / 8320, v = u - b * 8320;
    int row, col, cs;
    if (v < 4224) {
      int rr = v / 2112;
      int rem = v - rr * 2112;
      row = rr * 65; col = rem >> 5; cs = rem & 31;
    } else {
      int v2 = v - 4224;
      row = 1 + (v2 >> 6);
      int rem = v2 & 63;
      col = (rem >> 5) * 65; cs = rem & 31;
    }
    size_t o = (((size_t)(b * XROW + row) * XROW + col) * 32 + cs) * 8;
    *reinterpret_cast<uint4*>(&xb2[o]) = make_uint4(0, 0, 0, 0);
  }
}

// ---------------- main: implicit-GEMM polyphase conv ----------------
// BM=128 (half the co*2+px rows, selected by mb), BN=128 (2 out sub-rows), 8 waves
// 4M x 2N, wave tile 32x64, 16x16x32 MFMA. LDS = 2x16KB A dbuf + 33.8KB X = 66.5KB
// -> TWO blocks/CU (grid 1024 = 2 exact residency rounds, 16 waves/CU). Mechanism:
// two INDEPENDENT barrier groups per CU — block B's MFMA hides block A's exposed
// VALU/LDS/barrier overhead (m114 co-scheduling). K-major 2-phase per step, A
// staged 1 step ahead via global_load_lds, X per cb restaged at boundary.
// launch_bounds(512,4): VGPR cap 128 — required for 2-block residency (watch spill).
__global__ __launch_bounds__(512, 4) void conv_main(
    const unsigned short* __restrict__ xb2,
    const unsigned short* __restrict__ gw3,
    const float* __restrict__ bias,
    float* __restrict__ out) {
  __shared__ __align__(16) unsigned char smem[32768 + 33792];
  unsigned short* at0 = (unsigned short*)smem;            // A buf 0: [128 row][64 ch]
  unsigned short* at1 = (unsigned short*)(smem + 16384);  // A buf 1
  unsigned short* xt = (unsigned short*)(smem + 32768);   // X: [4 xrow][66 col][8 slot][16B]

  const int bid = blockIdx.x;
  const int b = bid & 7;             // XCD b-affinity
  const int m0 = ((bid >> 3) & 31) * 2;  // first of 2 output sub-rows
  const int mb = (bid >> 8) & 1;     // M half: rows mb*128..mb*128+127
  const int py = bid >> 9;           // 0..1

  const int t = threadIdx.x;
  const int lane = t & 63;
  const int wave = t >> 6;
  const int wmi = wave >> 1;  // 0..3: M sub-slice (32 rows)
  const int wn = wave & 1;    // 0..1: output sub-row
  const int l15 = lane & 15, l4 = lane >> 4;

  f32x4 acc[2][4] = {};

  const char* xbase = (const char*)xb2 + (size_t)((b * XROW + m0) * (XROW * 32)) * 16;
  const char* gw3b = (const char*)gw3;

  // stage one 8KB half of the next A sub-tile (1 gload/thread)
#define STAGE_A_HALF(buf, de_, cb_, H)                                                \
  do {                                                                                \
    const char* g = gw3b + ((((size_t)(de_)*2 + py) * 4 + (cb_)) << 15) +             \
                    mb * 16384 + (H)*8192;                                            \
    gload_lds16(g + t * 16, (char*)(buf) + (H)*8192 + t * 16);                        \
  } while (0)

  // X tile per cb: [4 xrow][66 col][8 slot] = 2112 16B units
#define STAGE_X(cb_)                                                          \
  do {                                                                        \
    for (int it = 0; it < 5; ++it) {                                          \
      int u = it * 512 + t;                                                   \
      if (u < 2112) {                                                         \
        int rr = u / 528;                                                     \
        int rem = u - rr * 528;                                               \
        int col = rem >> 3, slot = rem & 7;                                   \
        size_t go = (size_t)(rr * XROW + col) * 32 + (cb_)*8 + slot;          \
        gload_lds16(xbase + go * 16, (char*)xt + (size_t)u * 16);             \
      }                                                                       \
    }                                                                         \
  } while (0)

#define BAR()                        \
  do {                               \
    asm volatile("" ::: "memory");   \
    __builtin_amdgcn_s_barrier();    \
    asm volatile("" ::: "memory");   \
  } while (0)

  // one K-half phase: 2 af + 4 bv ds_read_b128 -> bar -> lgkm(0) -> 8 MFMA
#define KPHASE(K8, XSTMT)                                                                 \
  do {                                                                                    \
    bf16x8 af[2], bfv[4];                                                                 \
    _Pragma("unroll") for (int i = 0; i < 2; ++i) {                                       \
      int row = wmi * 32 + i * 16 + l15;  /* local; global row&7 == l15&7 */              \
      int slot = ((K8)*4 + l4) ^ (l15 & 7);                                               \
      af[i] = *(const bf16x8*)(A + (size_t)row * 64 + slot * 8);                          \
    }                                                                                     \
    _Pragma("unroll") for (int j = 0; j < 4; ++j) {                                       \
      int col = j * 16 + l15 + e;                                                         \
      int slot = ((K8)*4 + l4) ^ (col & 7);                                               \
      bfv[j] = *(const bf16x8*)(xt + ((size_t)xr * 66 + col) * 64 + slot * 8);            \
    }                                                                                     \
    BAR();                                                                                \
    XSTMT;                                                                                \
    asm volatile("s_waitcnt lgkmcnt(0)" ::: "memory");                                    \
    __builtin_amdgcn_sched_barrier(0);                                                    \
    __builtin_amdgcn_s_setprio(1);                                                        \
    _Pragma("unroll") for (int i = 0; i < 2; ++i)                                         \
      _Pragma("unroll") for (int j = 0; j < 4; ++j)                                       \
        acc[i][j] =                                                                       \
            __builtin_amdgcn_mfma_f32_16x16x32_bf16(af[i], bfv[j], acc[i][j], 0, 0, 0);   \
    __builtin_amdgcn_s_setprio(0);                                                        \
  } while (0)

  // prologue: first A sub-tile + first X tile
  STAGE_A_HALF(at0, 0, 0, 0);
  STAGE_A_HALF(at0, 0, 0, 1);
  STAGE_X(0);
  asm volatile("s_waitcnt vmcnt(0)" ::: "memory");
  BAR();

  unsigned short* A = at0;
  unsigned short* An = at1;
  int cb = 0, de = 0, d = 0, e = 0;
  for (int s = 0; s < 36; ++s) {
    const int xr = wn + d;
    const int notlast = (s < 35);
    const int nde = (de == 8) ? 0 : de + 1;
    const int ncb = (de == 8) ? cb + 1 : cb;

    if (notlast) STAGE_A_HALF(An, nde, ncb, 0);
    KPHASE(0, {});
    BAR();
    if (notlast) STAGE_A_HALF(An, nde, ncb, 1);
    KPHASE(1, {
      if (de == 8 && cb < 3) STAGE_X(cb + 1);  // xt reads done at this phase's barrier
    });
    asm volatile("s_waitcnt vmcnt(0)" ::: "memory");  // next A (+X at boundary) complete
    BAR();

    { unsigned short* tmp = A; A = An; An = tmp; }
    ++e;
    if (e == 3) { e = 0; ++d; }
    ++de;
    if (de == 9) { de = 0; d = 0; e = 0; ++cb; }
  }
#undef STAGE_A_HALF
#undef STAGE_X
#undef KPHASE

  const float kSqrt2 = 1.41421356237309515f;
  const int oh = 2 * (m0 + wn) + py;
#pragma unroll
  for (int i = 0; i < 2; ++i) {
    const int row0 = mb * 128 + wmi * 32 + i * 16 + l4 * 4;  // even
    const int co0 = row0 >> 1;                    // r=0,1 -> co0 (px=0,1); r=2,3 -> co0+1
    const float bs0 = bias[co0], bs1 = bias[co0 + 1];
#pragma unroll
    for (int j = 0; j < 4; ++j) {
      const int n = j * 16 + l15;
      float v[4];
#pragma unroll
      for (int r = 0; r < 4; ++r) {
        float vv = acc[i][j][r] + ((r < 2) ? bs0 : bs1);
        vv = (vv < 0.f ? 0.01f * vv : vv) * kSqrt2;
        v[r] = fminf(fmaxf(vv, -256.f), 265.f);
      }
      float2* p0 = (float2*)&out[(((size_t)b * COUT + co0) * 128 + oh) * 128 + 2 * n];
      float2* p1 = (float2*)&out[(((size_t)b * COUT + co0 + 1) * 128 + oh) * 128 + 2 * n];
      *p0 = make_float2(v[0], v[1]);
      *p1 = make_float2(v[2], v[3]);
    }
  }
}

extern "C" void kernel_launch(void* const* d_in, const int* in_sizes, int n_in,
                              void* d_out, int out_size, void* d_ws, size_t ws_size,
                              hipStream_t stream) {
  const float* x = (const float*)d_in[0];
  const float* w = (const float*)d_in[1];
  const float* bias = (const float*)d_in[2];
  const float* f = (const float*)d_in[3];
  float* out = (float*)d_out;

  unsigned short* xb2 = (unsigned short*)d_ws;
  unsigned short* gw3 = (unsigned short*)((char*)d_ws + XB2_BYTES);

  hipLaunchKernelGGL(prep_all, dim3(900), dim3(256), 0, stream, x, w, f, xb2, gw3);
  hipLaunchKernelGGL(conv_main, dim3(1024), dim3(512), 0, stream, xb2, gw3, bias, out);
}

// Round 13
// 76.635 us; speedup vs baseline: 1.1612x; 1.1612x over previous
//
#include <hip/hip_runtime.h>
#include <stdint.h>

#define CIN 256
#define COUT 128
#define BATCH 8
#define HH 64
#define WW 64
#define XROW 66

// xb2: padded bf16 input, [B][66 rows][66 cols][4 cb][8 slot][8 ch], slot pre-swizzled by (col&7)
#define XB2_BYTES ((size_t)BATCH * XROW * XROW * CIN * 2)
// gw3: fused weights, UNSWIZZLED: [9 taps][2 py][4 cb][256 row=co*2+px][8 g][8 ch]
#define GW3_BYTES ((size_t)9 * 2 * 4 * 256 * 64 * 2)

typedef __bf16 bf16x8 __attribute__((ext_vector_type(8)));
typedef float f32x4 __attribute__((ext_vector_type(4)));

__device__ __forceinline__ unsigned short f2bf(float f) {
  unsigned int u = __float_as_uint(f);
  u += 0x7fffu + ((u >> 16) & 1u);
  return (unsigned short)(u >> 16);
}

__device__ __forceinline__ void gload_lds16(const void* g, void* l) {
  __builtin_amdgcn_global_load_lds(
      (__attribute__((address_space(1))) void*)(uintptr_t)g,
      (__attribute__((address_space(3))) void*)l, 16, 0, 0);
}

// ---------------- fused prep: prep_x (512 blk) + prep_w (128 blk) + border (260 blk) ----------------
__global__ __launch_bounds__(256) void prep_all(const float* __restrict__ x,
                                                const float* __restrict__ w,
                                                const float* __restrict__ f,
                                                unsigned short* __restrict__ xb2,
                                                unsigned short* __restrict__ gw3) {
  __shared__ __align__(16) unsigned short lds[64][264];  // prep_x staging; fs aliases it
  const int blk = blockIdx.x;
  const int t = threadIdx.x;

  if (blk < 512) {
    // ---- prep_x: x -> padded channel-last swizzled bf16 (interior) ----
    int b = blk >> 6, iy = blk & 63;
    int cq = t >> 6, ix = t & 63;
    for (int ci = 0; ci < 64; ++ci) {
      int c = ci * 4 + cq;
      float v = x[(((size_t)b * CIN + c) * HH + iy) * WW + ix];
      lds[ix][c] = f2bf(v);
    }
    __syncthreads();
    for (int it = 0; it < 8; ++it) {
      int u = it * 256 + t;  // 2048 units of 16B: 64 ix * 32 (cb,slot)
      int ixo = u >> 5;
      int q = u & 31, cb = q >> 3, slot = q & 7;
      int col = ixo + 1;  // padded col
      int c0 = cb * 64 + 8 * (slot ^ (col & 7));
      uint4 val = *reinterpret_cast<const uint4*>(&lds[ixo][c0]);
      size_t o = ((((size_t)(b * XROW + (iy + 1)) * XROW + col) * 4 + cb) * 8 + slot) * 8;
      *reinterpret_cast<uint4*>(&xb2[o]) = val;
    }
  } else if (blk < 640) {
    // ---- prep_w: fuse He-scale * conv3x3 (x) FIR; stored UNSWIZZLED [row][g][8ch] ----
    float* fs = (float*)lds;
    int co = blk - 512;
    int c = t;
    if (c < 16) fs[c] = f[c];
    __syncthreads();
    float wl[3][3];
    const float he = 1.0f / 48.0f;  // 1/sqrt(256*9)
#pragma unroll
    for (int dy = 0; dy < 3; ++dy)
#pragma unroll
      for (int dx = 0; dx < 3; ++dx)
        wl[dy][dx] = w[((size_t)(co * CIN + c) * 3 + dy) * 3 + dx] * he;
    int cb = c >> 6, cl = c & 63;
    int g = cl >> 3;  // logical channel group, NO pre-swizzle (swizzle applied at stage time)
    int ce = cl & 7;
    for (int d = 0; d < 3; ++d)
      for (int e = 0; e < 3; ++e)
        for (int py = 0; py < 2; ++py)
          for (int px = 0; px < 2; ++px) {
            int ty = 2 * d + 1 - py, tx = 2 * e + 1 - px;  // taps of 6x6 composite g
            float acc = 0.f;
            for (int dy = 0; dy < 3; ++dy) {
              int a = ty - dy;
              if (a < 0 || a > 3) continue;
              for (int dx = 0; dx < 3; ++dx) {
                int bb = tx - dx;
                if (bb < 0 || bb > 3) continue;
                acc += wl[dy][dx] * fs[a * 4 + bb];
              }
            }
            int row = co * 2 + px;
            size_t o =
                ((((size_t)(d * 3 + e) * 2 + py) * 4 + cb) * 256 + row) * 64 + g * 8 + ce;
            gw3[o] = f2bf(acc);
          }
  } else {
    // ---- border zeroing ----
    int u = (blk - 640) * 256 + t;
    if (u >= 66560) return;
    int b = u / 8320, v = u - b * 8320;
    int row, col, cs;
    if (v < 4224) {
      int rr = v / 2112;
      int rem = v - rr * 2112;
      row = rr * 65; col = rem >> 5; cs = rem & 31;
    } else {
      int v2 = v - 4224;
      row = 1 + (v2 >> 6);
      int rem = v2 & 63;
      col = (rem >> 5) * 65; cs = rem & 31;
    }
    size_t o = (((size_t)(b * XROW + row) * XROW + col) * 32 + cs) * 8;
    *reinterpret_cast<uint4*>(&xb2[o]) = make_uint4(0, 0, 0, 0);
  }
}

// ---------------- main: implicit-GEMM polyphase conv ----------------
// BM=128 (weight rows mb*128..+127), BN=256 (4 out sub-rows), 4 waves (1M x 4N),
// wave tile 128x64 (r = 12 LDS reads / 32 MFMA = 0.375 — LDS-pipe time ~= MFMA time).
// LDS 65.5KB -> TWO independent blocks/CU (grid 512 exact-resident, 8 waves/CU):
// block B's MFMA covers block A's read/barrier windows (m114; R12 showed partial
// cross-block overlap). A-tile: two 8KB k8-half buffers, each restaged IN-PLACE
// right after its reads complete (gated by the step's 2 barriers; every vmcnt(0)
// drains loads issued ~a phase earlier — no drain stalls, no dbuf LDS cost).
// Swizzle moved to the GLOBAL side (gw3 unswizzled; per-lane stage addrs apply it).
__global__ __launch_bounds__(256, 2) void conv_main(
    const unsigned short* __restrict__ xb2,
    const unsigned short* __restrict__ gw3,
    const float* __restrict__ bias,
    float* __restrict__ out) {
  __shared__ __align__(16) unsigned char smem[8192 + 8192 + 50688];
  unsigned short* ah0 = (unsigned short*)smem;            // A k8=0 half: [128 row][4 qp][16B]
  unsigned short* ah1 = (unsigned short*)(smem + 8192);   // A k8=1 half
  unsigned short* xt = (unsigned short*)(smem + 16384);   // X: [6 xrow][66 col][8 slot][16B]

  const int bid = blockIdx.x;
  const int b = bid & 7;              // XCD b-affinity
  const int mg = (bid >> 3) & 15;
  const int mb = (bid >> 7) & 1;      // weight-row half
  const int py = (bid >> 8) & 1;
  const int m0 = mg * 4;              // 4 output sub-rows per block

  const int t = threadIdx.x;
  const int lane = t & 63;
  const int wn = t >> 6;              // wave 0..3 = output sub-row
  const int l15 = lane & 15, l4 = lane >> 4;
  const int qpc = l4 ^ ((l15 >> 1) & 3);  // af physical slot (lane-constant)

  f32x4 acc[8][4] = {};

  const char* xbase = (const char*)xb2 + (size_t)((b * XROW + m0) * (XROW * 32)) * 16;
  const char* gw3b = (const char*)gw3 + mb * 16384;

  // stage one 8KB k8-half of A for tap (de,cb): 512 units, 2 gloads/thread.
  // global row*128 + g*16 with g = k8*4 + (qp ^ ((row>>1)&3)); LDS linear [row][qp].
#define STAGE_AH(DSTH, K8, de_, cb_)                                                   \
  do {                                                                                 \
    const char* g_ = gw3b + ((((size_t)(de_)*2 + py) * 4 + (cb_)) << 15);              \
    _Pragma("unroll") for (int it = 0; it < 2; ++it) {                                 \
      int u = it * 256 + t;                                                            \
      int lrow = u >> 2, qp = u & 3;                                                   \
      int gg = (K8)*4 + (qp ^ ((lrow >> 1) & 3));                                      \
      gload_lds16(g_ + lrow * 128 + gg * 16, (char*)(DSTH) + u * 16);                  \
    }                                                                                  \
  } while (0)

  // X tile per cb: 6 rows x 66 cols x 8 slots = 3168 16B units; 13 iters of 256
#define STAGE_X(cb_)                                                          \
  do {                                                                        \
    int rr_ = 0, rem_ = t;                                                    \
    for (int it = 0; it < 13; ++it) {                                         \
      int u = it * 256 + t;                                                   \
      if (u < 3168) {                                                         \
        int col = rem_ >> 3, slot = rem_ & 7;                                 \
        size_t go = (size_t)(rr_ * XROW + col) * 32 + (cb_)*8 + slot;         \
        gload_lds16(xbase + go * 16, (char*)xt + (size_t)u * 16);             \
      }                                                                       \
      rem_ += 256;                                                            \
      if (rem_ >= 528) { rem_ -= 528; ++rr_; }                                \
    }                                                                         \
  } while (0)

#define BAR()                        \
  do {                               \
    asm volatile("" ::: "memory");   \
    __builtin_amdgcn_s_barrier();    \
    asm volatile("" ::: "memory");   \
  } while (0)

#define READ_AF(AF, AH)                                                                \
  do {                                                                                 \
    _Pragma("unroll") for (int i = 0; i < 8; ++i)                                      \
        (AF)[i] = *(const bf16x8*)((const char*)(AH) + i * 1024 + l15 * 64 + qpc * 16);\
  } while (0)

#define READ_BV(BV, K8)                                                                \
  do {                                                                                 \
    _Pragma("unroll") for (int j = 0; j < 4; ++j) {                                    \
      int col = j * 16 + l15 + e;                                                      \
      int slot = ((K8)*4 + l4) ^ (col & 7);                                            \
      (BV)[j] = *(const bf16x8*)(xt + ((size_t)xr * 66 + col) * 64 + slot * 8);        \
    }                                                                                  \
  } while (0)

#define MFMA32(AF, BV)                                                                   \
  do {                                                                                   \
    asm volatile("s_waitcnt lgkmcnt(0)" ::: "memory");                                   \
    __builtin_amdgcn_sched_barrier(0);                                                   \
    __builtin_amdgcn_s_setprio(1);                                                       \
    _Pragma("unroll") for (int i = 0; i < 8; ++i)                                        \
      _Pragma("unroll") for (int j = 0; j < 4; ++j)                                      \
        acc[i][j] =                                                                      \
            __builtin_amdgcn_mfma_f32_16x16x32_bf16((AF)[i], (BV)[j], acc[i][j], 0, 0, 0); \
    __builtin_amdgcn_s_setprio(0);                                                       \
  } while (0)

  // prologue: A halves (s=0) + X(cb=0); full drain; barrier
  STAGE_AH(ah0, 0, 0, 0);
  STAGE_AH(ah1, 1, 0, 0);
  STAGE_X(0);
  asm volatile("s_waitcnt vmcnt(0)" ::: "memory");
  BAR();

  int cb = 0, de = 0, d = 0, e = 0;
  for (int s = 0; s < 36; ++s) {
    const int xr = wn + d;
    const int notlast = (s < 35);
    const int nde = (de == 8) ? 0 : de + 1;
    const int ncb = (de == 8) ? cb + 1 : cb;
    const int boundary = (de == 8) && (cb < 3);

    bf16x8 af[8], bv[4];

    // ---- phase 0 (k8=0) ----
    READ_AF(af, ah0);
    READ_BV(bv, 0);
    asm volatile("s_waitcnt vmcnt(0)" ::: "memory");  // drain prev step's ah1 stage
    BAR();                                            // #1: ah0 reads done by all waves
    if (notlast) STAGE_AH(ah0, 0, nde, ncb);          // restage ah0 in place
    MFMA32(af, bv);

    // ---- phase 1 (k8=1) ----
    READ_AF(af, ah1);
    READ_BV(bv, 1);
    asm volatile("s_waitcnt vmcnt(0)" ::: "memory");  // drain my ah0 stage (issued ~1 phase ago)
    BAR();                                            // #2: ah1 + xt reads done by all waves
    if (boundary) STAGE_X(cb + 1);
    if (notlast) STAGE_AH(ah1, 1, nde, ncb);          // restage ah1 in place
    if (boundary) {
      // X' must be visible to next step's phase-0 bv reads: drain all but ah1's 2, fence
      asm volatile("s_waitcnt vmcnt(2)" ::: "memory");
      BAR();
    }
    MFMA32(af, bv);

    d = (nde == 0) ? 0 : ((e == 2) ? d + 1 : d);
    e = (nde == 0) ? 0 : ((e == 2) ? 0 : e + 1);
    de = nde; cb = ncb;
  }
#undef STAGE_AH
#undef STAGE_X
#undef READ_AF
#undef READ_BV
#undef MFMA32

  const float kSqrt2 = 1.41421356237309515f;
  const int oh = 2 * (m0 + wn) + py;
#pragma unroll
  for (int i = 0; i < 8; ++i) {
    const int row0 = mb * 128 + i * 16 + l4 * 4;  // even
    const int co0 = row0 >> 1;                    // r=0,1 -> co0 (px=0,1); r=2,3 -> co0+1
    const float bs0 = bias[co0], bs1 = bias[co0 + 1];
#pragma unroll
    for (int j = 0; j < 4; ++j) {
      const int n = j * 16 + l15;
      float v[4];
#pragma unroll
      for (int r = 0; r < 4; ++r) {
        float vv = acc[i][j][r] + ((r < 2) ? bs0 : bs1);
        vv = (vv < 0.f ? 0.01f * vv : vv) * kSqrt2;
        v[r] = fminf(fmaxf(vv, -256.f), 265.f);
      }
      float2* p0 = (float2*)&out[(((size_t)b * COUT + co0) * 128 + oh) * 128 + 2 * n];
      float2* p1 = (float2*)&out[(((size_t)b * COUT + co0 + 1) * 128 + oh) * 128 + 2 * n];
      *p0 = make_float2(v[0], v[1]);
      *p1 = make_float2(v[2], v[3]);
    }
  }
}

extern "C" void kernel_launch(void* const* d_in, const int* in_sizes, int n_in,
                              void* d_out, int out_size, void* d_ws, size_t ws_size,
                              hipStream_t stream) {
  const float* x = (const float*)d_in[0];
  const float* w = (const float*)d_in[1];
  const float* bias = (const float*)d_in[2];
  const float* f = (const float*)d_in[3];
  float* out = (float*)d_out;

  unsigned short* xb2 = (unsigned short*)d_ws;
  unsigned short* gw3 = (unsigned short*)((char*)d_ws + XB2_BYTES);

  hipLaunchKernelGGL(prep_all, dim3(900), dim3(256), 0, stream, x, w, f, xb2, gw3);
  hipLaunchKernelGGL(conv_main, dim3(512), dim3(256), 0, stream, xb2, gw3, bias, out);
}